// Round 5
// baseline (615.756 us; speedup 1.0000x reference)
//
#include <hip/hip_runtime.h>

#define N_ROWS   131072
#define D_IN     512
#define D_H      128
#define K_CODES  256
#define NT       256          // 4 waves
#define RPB      64           // rows per block: 16 per wave
#define NBLK     (N_ROWS / RPB)

typedef __attribute__((ext_vector_type(8))) short bf16x8;
typedef __attribute__((ext_vector_type(4))) float f32x4;

__device__ inline unsigned short f2bf(float f) {
    unsigned u = __float_as_uint(f);
    return (unsigned short)((u + 0x7FFFu + ((u >> 16) & 1u)) >> 16);
}
__device__ inline ushort4 f2bf4(float4 v) {
    return make_ushort4(f2bf(v.x), f2bf(v.y), f2bf(v.z), f2bf(v.w));
}
__device__ inline bf16x8 f2bf8(float4 v0, float4 v1) {
    bf16x8 r;
    r[0] = (short)f2bf(v0.x); r[1] = (short)f2bf(v0.y);
    r[2] = (short)f2bf(v0.z); r[3] = (short)f2bf(v0.w);
    r[4] = (short)f2bf(v1.x); r[5] = (short)f2bf(v1.y);
    r[6] = (short)f2bf(v1.z); r[7] = (short)f2bf(v1.w);
    return r;
}

// ---------------- prep: weights/codebooks -> bf16 MFMA B-fragment order ----------------
// frag(ct,ks): 64 lanes x 8 bf16; lane qd*16+nn holds B[n=ct*16+nn][k=ks*32+qd*8+j].
// wsb (ushorts): [0..65535] Wenc (kc=0..3) | [65536..163839] cb (t,half) | [163840..229375] Wdec (c=0..3)
__global__ void rqvae_prep(const float* __restrict__ Wenc,
                           const float* __restrict__ Wdec,
                           const float* __restrict__ cb0,
                           const float* __restrict__ cb1,
                           const float* __restrict__ cb2,
                           unsigned short* __restrict__ wsb,
                           float* __restrict__ norms)
{
    const int tid = threadIdx.x;
    const int b = blockIdx.x;
    const float* cbs[3] = {cb0, cb1, cb2};
    if (b < 112) {
        const int g = b * 256 + tid;            // ushort8 group id, 0..28671
        const int lane = g & 63, ks = (g >> 6) & 3, ct = (g >> 8) & 7;
        const int nn = lane & 15, qd = lane >> 4;
        const float* src;
        if (g < 8192) {                         // Wenc
            const int kc = g >> 11;
            src = Wenc + (ct * 16 + nn) * D_IN + kc * 128 + ks * 32 + qd * 8;
        } else if (g < 20480) {                 // cb
            const int r = g - 8192;
            const int t = r >> 12, half = (r >> 11) & 1;
            src = cbs[t] + (long)(half * 128 + ct * 16 + nn) * D_H + ks * 32 + qd * 8;
        } else {                                // Wdec
            const int r = g - 20480;
            const int c = r >> 11;
            src = Wdec + (long)(c * 128 + ct * 16 + nn) * D_H + ks * 32 + qd * 8;
        }
        float4 v0 = *(const float4*)(src);
        float4 v1 = *(const float4*)(src + 4);
        *(ushort4*)(wsb + (long)g * 8)     = f2bf4(v0);
        *(ushort4*)(wsb + (long)g * 8 + 4) = f2bf4(v1);
    } else {
        const int t = b - 112;
        const float4* r = (const float4*)(cbs[t] + (long)tid * D_H);
        float s = 0.f;
        #pragma unroll
        for (int d = 0; d < 32; ++d) { float4 v = r[d]; s += v.x*v.x + v.y*v.y + v.z*v.z + v.w*v.w; }
        norms[t * K_CODES + tid] = -0.5f * s;
    }
}

// ---------------- main ----------------
__global__ __launch_bounds__(NT, 3) void rqvae_main(
    const float* __restrict__ emb,
    const float* __restrict__ cb0,
    const float* __restrict__ cb1,
    const float* __restrict__ cb2,
    const unsigned short* __restrict__ wsb,
    const float* __restrict__ norms,
    float* __restrict__ acc_rq,
    float* __restrict__ acc_recon,
    int* __restrict__ used)
{
    __shared__ unsigned short s_B[16384];   // 32 KB: one B round, fragment-linear
    __shared__ unsigned short s_A[8192];    // 16 KB: rem/restored tile, fragment order
    __shared__ float s_cn[K_CODES];         // 1 KB : current-stage -0.5*||c||^2

    const int tid  = threadIdx.x;
    const int wv   = tid >> 6;
    const int lane = tid & 63;
    const int nn   = lane & 15;
    const int qd   = lane >> 4;
    const long blkRow = (long)blockIdx.x * RPB;
    const float* cbs[3] = {cb0, cb1, cb2};

    f32x4 rem[8], res[8];
    #pragma unroll
    for (int ct = 0; ct < 8; ++ct) { rem[ct] = {0.f,0.f,0.f,0.f}; res[ct] = {0.f,0.f,0.f,0.f}; }

    // ---- Phase 1: latent = emb @ Wenc^T (4 rounds of K=128); A direct to registers ----
    const float* arow = emb + (blkRow + wv * 16 + nn) * D_IN + qd * 8;
    for (int kc = 0; kc < 4; ++kc) {
        __syncthreads();
        {   // B: 32 KB fragment-linear copy (L2-hot)
            const bf16x8* src = (const bf16x8*)(wsb + kc * 16384);
            bf16x8* dst = (bf16x8*)s_B;
            #pragma unroll
            for (int i = 0; i < 8; ++i) dst[tid + i * NT] = src[tid + i * NT];
        }
        // A fragments straight from global fp32
        bf16x8 af[4];
        #pragma unroll
        for (int ks = 0; ks < 4; ++ks) {
            float4 v0 = *(const float4*)(arow + kc * 128 + ks * 32);
            float4 v1 = *(const float4*)(arow + kc * 128 + ks * 32 + 4);
            af[ks] = f2bf8(v0, v1);
        }
        __syncthreads();
        #pragma unroll
        for (int ct = 0; ct < 8; ++ct)
            #pragma unroll
            for (int ks = 0; ks < 4; ++ks) {
                bf16x8 bf = *(const bf16x8*)&s_B[(ct * 4 + ks) * 512 + lane * 8];
                rem[ct] = __builtin_amdgcn_mfma_f32_16x16x32_bf16(af[ks], bf, rem[ct], 0, 0, 0);
            }
    }

    // C-layout (row=qd*4+e, col=ct*16+nn) -> A-frag order in s_A (wave-private region)
    #pragma unroll
    for (int ct = 0; ct < 8; ++ct)
        #pragma unroll
        for (int e = 0; e < 4; ++e)
            s_A[(wv * 4 + (ct >> 1)) * 512 +
                (((((ct & 1) << 1) | (nn >> 3)) * 16) + qd * 4 + e) * 8 + (nn & 7)] = f2bf(rem[ct][e]);

    // ---- Phase 2: three RQ stages ----
    float local_rq = 0.f;
    for (int t = 0; t < 3; ++t) {
        const float* __restrict__ cb = cbs[t];
        bf16x8 af[4];
        #pragma unroll
        for (int ks = 0; ks < 4; ++ks)
            af[ks] = *(const bf16x8*)&s_A[(wv * 4 + ks) * 512 + lane * 8];
        float bv[4]; int bi[4];
        #pragma unroll
        for (int e = 0; e < 4; ++e) { bv[e] = -3.402823466e38f; bi[e] = 0; }

        for (int half = 0; half < 2; ++half) {
            __syncthreads();
            if (half == 0) s_cn[tid] = norms[t * K_CODES + tid];
            {
                const bf16x8* src = (const bf16x8*)(wsb + 65536 + (t * 2 + half) * 16384);
                bf16x8* dst = (bf16x8*)s_B;
                #pragma unroll
                for (int i = 0; i < 8; ++i) dst[tid + i * NT] = src[tid + i * NT];
            }
            __syncthreads();
            #pragma unroll
            for (int ct = 0; ct < 8; ++ct) {
                f32x4 sc = {0.f,0.f,0.f,0.f};
                #pragma unroll
                for (int ks = 0; ks < 4; ++ks) {
                    bf16x8 bf = *(const bf16x8*)&s_B[(ct * 4 + ks) * 512 + lane * 8];
                    sc = __builtin_amdgcn_mfma_f32_16x16x32_bf16(af[ks], bf, sc, 0, 0, 0);
                }
                const int code = half * 128 + ct * 16 + nn;
                const float cn = s_cn[code];
                #pragma unroll
                for (int e = 0; e < 4; ++e) {
                    const float v = sc[e] + cn;
                    if (v > bv[e] || (v == bv[e] && code < bi[e])) { bv[e] = v; bi[e] = code; }
                }
            }
        }
        // argmax over the 16 nn-lanes of each quad (tie -> lowest index)
        #pragma unroll
        for (int e = 0; e < 4; ++e) {
            float v = bv[e]; int i0 = bi[e];
            #pragma unroll
            for (int m = 8; m >= 1; m >>= 1) {
                const float ov = __shfl_xor(v, m);
                const int   oi = __shfl_xor(i0, m);
                if (ov > v || (ov == v && oi < i0)) { v = ov; i0 = oi; }
            }
            bi[e] = i0;
            if (nn == 0) used[t * K_CODES + i0] = 1;
        }
        // update rem/res with fp32 codebook rows; stash rem for next stage
        #pragma unroll
        for (int ct = 0; ct < 8; ++ct)
            #pragma unroll
            for (int e = 0; e < 4; ++e) {
                const float c = cb[(long)bi[e] * D_H + ct * 16 + nn];
                const float r = rem[ct][e] - c;
                rem[ct][e] = r;
                res[ct][e] += c;
                local_rq += r * r;
                if (t < 2)
                    s_A[(wv * 4 + (ct >> 1)) * 512 +
                        (((((ct & 1) << 1) | (nn >> 3)) * 16) + qd * 4 + e) * 8 + (nn & 7)] = f2bf(r);
            }
    }

    // restored -> s_A frag order
    #pragma unroll
    for (int ct = 0; ct < 8; ++ct)
        #pragma unroll
        for (int e = 0; e < 4; ++e)
            s_A[(wv * 4 + (ct >> 1)) * 512 +
                (((((ct & 1) << 1) | (nn >> 3)) * 16) + qd * 4 + e) * 8 + (nn & 7)] = f2bf(res[ct][e]);

    // ---- Phase 3: recon = restored @ Wdec^T, diff vs fp32 emb ----
    float local_rec = 0.f;
    {
        bf16x8 af[4];
        #pragma unroll
        for (int ks = 0; ks < 4; ++ks)
            af[ks] = *(const bf16x8*)&s_A[(wv * 4 + ks) * 512 + lane * 8];
        for (int c = 0; c < 4; ++c) {
            __syncthreads();
            {
                const bf16x8* src = (const bf16x8*)(wsb + 163840 + c * 16384);
                bf16x8* dst = (bf16x8*)s_B;
                #pragma unroll
                for (int i = 0; i < 8; ++i) dst[tid + i * NT] = src[tid + i * NT];
            }
            __syncthreads();
            #pragma unroll
            for (int ct = 0; ct < 8; ++ct) {
                f32x4 rc = {0.f,0.f,0.f,0.f};
                #pragma unroll
                for (int ks = 0; ks < 4; ++ks) {
                    bf16x8 bf = *(const bf16x8*)&s_B[(ct * 4 + ks) * 512 + lane * 8];
                    rc = __builtin_amdgcn_mfma_f32_16x16x32_bf16(af[ks], bf, rc, 0, 0, 0);
                }
                const int col = c * 128 + ct * 16 + nn;
                #pragma unroll
                for (int e = 0; e < 4; ++e) {
                    const float ev = emb[(blkRow + wv * 16 + qd * 4 + e) * D_IN + col];
                    const float d = rc[e] - ev;
                    local_rec += d * d;
                }
            }
        }
    }

    // ---- wave shuffle reduce, one atomic pair per wave ----
    float r1 = local_rq, r2 = local_rec;
    #pragma unroll
    for (int m = 32; m >= 1; m >>= 1) { r1 += __shfl_xor(r1, m); r2 += __shfl_xor(r2, m); }
    if (lane == 0) { atomicAdd(acc_rq, r1); atomicAdd(acc_recon, r2); }
}

__global__ void rqvae_finalize(const float* __restrict__ acc,
                               const int* __restrict__ used,
                               float* __restrict__ out)
{
    __shared__ int s_sum[4];
    const int tid = threadIdx.x;
    for (int t = 0; t < 3; ++t) {
        int v = (used[t * K_CODES + tid] != 0) ? 1 : 0;
        #pragma unroll
        for (int off = 32; off >= 1; off >>= 1) v += __shfl_down(v, off);
        if ((tid & 63) == 0) s_sum[tid >> 6] = v;
        __syncthreads();
        if (tid == 0) out[3 + t] = (float)(s_sum[0] + s_sum[1] + s_sum[2] + s_sum[3]);
        __syncthreads();
    }
    if (tid == 0) {
        const float rq    = 1.25f * acc[0] / ((float)N_ROWS * 128.0f);
        const float recon =         acc[1] / ((float)N_ROWS * 512.0f);
        out[0] = recon + rq;
        out[1] = recon;
        out[2] = rq;
    }
}

extern "C" void kernel_launch(void* const* d_in, const int* in_sizes, int n_in,
                              void* d_out, int out_size, void* d_ws, size_t ws_size,
                              hipStream_t stream) {
    const float* emb  = (const float*)d_in[0];
    const float* Wenc = (const float*)d_in[1];
    const float* Wdec = (const float*)d_in[2];
    const float* cb0  = (const float*)d_in[3];
    const float* cb1  = (const float*)d_in[4];
    const float* cb2  = (const float*)d_in[5];

    // ws layout (bytes): [0] 2 f32 acc | [64] 768 int used | [3200] 768 f32 norms | [8192] 448KB bf16 frags
    float* ws_f  = (float*)d_ws;
    int*   used  = (int*)((char*)d_ws + 64);
    float* norms = (float*)((char*)d_ws + 3200);
    unsigned short* wsb = (unsigned short*)((char*)d_ws + 8192);

    hipMemsetAsync(d_ws, 0, 3200, stream);
    rqvae_prep<<<115, NT, 0, stream>>>(Wenc, Wdec, cb0, cb1, cb2, wsb, norms);
    rqvae_main<<<NBLK, NT, 0, stream>>>(emb, cb0, cb1, cb2, wsb, norms,
                                        ws_f + 0, ws_f + 1, used);
    rqvae_finalize<<<1, K_CODES, 0, stream>>>(ws_f, used, (float*)d_out);
}